// Round 6
// baseline (616.803 us; speedup 1.0000x reference)
//
#include <hip/hip_runtime.h>
#include <hip/hip_bf16.h>
#include <stdint.h>

#define N_TOK 2048
#define H_DIM 1024
#define F_DIM 2816
#define N_EXP 8

#define BK 64
#define LDA 72   // padded LDS row stride in bf16 elems (16B-aligned)

typedef __attribute__((ext_vector_type(8))) short bf16x8;
typedef __attribute__((ext_vector_type(4))) float f32x4;

static __device__ __forceinline__ unsigned short f2bf(float f) {
    union { float f; unsigned u; } v; v.f = f;
    unsigned r = v.u + 0x7fffu + ((v.u >> 16) & 1u);   // round-to-nearest-even
    return (unsigned short)(r >> 16);
}
static __device__ __forceinline__ unsigned pk2(float a, float b) {
    return (unsigned)f2bf(a) | ((unsigned)f2bf(b) << 16);
}

// ---------------- Router: 1 wave per token; also emits x in bf16 ----------------
__global__ __launch_bounds__(256) void router_kernel(
    const float* __restrict__ x, const float* __restrict__ gate_w,
    int* __restrict__ counts, int* __restrict__ row_token, float* __restrict__ row_weight,
    int* __restrict__ slot_e, int* __restrict__ slot_pos,
    unsigned short* __restrict__ xb)
{
    __shared__ float gsm[N_EXP * H_DIM];
    for (int i = threadIdx.x; i < N_EXP * H_DIM; i += 256) gsm[i] = gate_w[i];
    __syncthreads();

    const int wave = threadIdx.x >> 6;
    const int lane = threadIdx.x & 63;
    const int n = blockIdx.x * 4 + wave;

    float xv[16];
#pragma unroll
    for (int i = 0; i < 16; i++) xv[i] = x[(size_t)n * H_DIM + lane + 64 * i];
#pragma unroll
    for (int i = 0; i < 16; i++) xb[(size_t)n * H_DIM + lane + 64 * i] = f2bf(xv[i]);

    float logit[N_EXP];
#pragma unroll
    for (int e = 0; e < N_EXP; e++) {
        float p = 0.f;
#pragma unroll
        for (int i = 0; i < 16; i++) p += xv[i] * gsm[e * H_DIM + lane + 64 * i];
#pragma unroll
        for (int s = 32; s > 0; s >>= 1) p += __shfl_xor(p, s, 64);
        logit[e] = p;
    }

    if (lane == 0) {
        int e0 = 0; float l0 = logit[0];
#pragma unroll
        for (int e = 1; e < N_EXP; e++) if (logit[e] > l0) { l0 = logit[e]; e0 = e; }
        int e1 = -1; float l1 = -3.4e38f;
#pragma unroll
        for (int e = 0; e < N_EXP; e++) if (e != e0 && logit[e] > l1) { l1 = logit[e]; e1 = e; }
        float w0 = 1.f / (1.f + __expf(l1 - l0));
        float w1 = 1.f - w0;
        int p0 = atomicAdd(&counts[e0], 1);
        int p1 = atomicAdd(&counts[e1], 1);
        row_token[e0 * N_TOK + p0] = n;  row_weight[e0 * N_TOK + p0] = w0;
        row_token[e1 * N_TOK + p1] = n;  row_weight[e1 * N_TOK + p1] = w1;
        slot_e[n * 2 + 0] = e0;  slot_pos[n * 2 + 0] = p0;
        slot_e[n * 2 + 1] = e1;  slot_pos[n * 2 + 1] = p1;
    }
}

// inline exclusive prefix over the 8 counts
static __device__ __forceinline__ int expert_off(const int* __restrict__ counts, int e) {
    int acc = 0;
#pragma unroll
    for (int i = 0; i < N_EXP; i++) if (i < e) acc += counts[i];
    return acc;
}

// ---------------- Up GEMM: act = silu(Xb_gather @ w1[e]^T), bf16 out -------------
// 512 threads = 8 waves, wave-tile 32x64 of the 128x128 block tile.
__global__ __launch_bounds__(512) void up_gemm_kernel(
    const unsigned short* __restrict__ xb, const float* __restrict__ w1,
    const int* __restrict__ counts,
    const int* __restrict__ row_token,
    unsigned short* __restrict__ act)
{
    const int e = blockIdx.z;
    const int cnt = counts[e];
    const int mTile = blockIdx.y;
    if (mTile * 128 >= cnt) return;
    const int fTile = blockIdx.x;
    const int off = expert_off(counts, e);

    __shared__ __align__(16) unsigned short As[128 * LDA];
    __shared__ __align__(16) unsigned short Bs[128 * LDA];

    const int tid = threadIdx.x;
    const int lane = tid & 63;
    const int wave = tid >> 6;                 // 0..7
    const int wm = (wave >> 1) * 32;           // 0,32,64,96
    const int wn = (wave & 1) * 64;            // 0,64
    const int srow = tid >> 2;                 // 0..127 (1 row / thread)
    const int sseg = tid & 3;                  // 4 x 16-elem segments per row

    const int tokenA = row_token[e * N_TOK + min(mTile * 128 + srow, cnt - 1)];

    f32x4 acc[2][4];
#pragma unroll
    for (int i = 0; i < 2; i++)
#pragma unroll
        for (int j = 0; j < 4; j++) acc[i][j] = (f32x4)(0.f);

    const unsigned short* abase = xb + (size_t)tokenA * H_DIM + sseg * 16;
    const float* wbase = w1 + (size_t)e * F_DIM * H_DIM + (size_t)(fTile * 128 + srow) * H_DIM + sseg * 16;

    uint4 ra[2];
    float4 rb[4];
    auto loadAB = [&](int kt) {
        const int k0 = kt * BK;
        ra[0] = *(const uint4*)(abase + k0);
        ra[1] = *(const uint4*)(abase + k0 + 8);
#pragma unroll
        for (int j = 0; j < 4; j++)
            rb[j] = *(const float4*)(wbase + k0 + j * 4);
    };
    auto stage = [&] {
        *(uint4*)(As + srow * LDA + sseg * 16)     = ra[0];
        *(uint4*)(As + srow * LDA + sseg * 16 + 8) = ra[1];
        uint4 b0;
        b0.x = pk2(rb[0].x, rb[0].y); b0.y = pk2(rb[0].z, rb[0].w);
        b0.z = pk2(rb[1].x, rb[1].y); b0.w = pk2(rb[1].z, rb[1].w);
        uint4 b1;
        b1.x = pk2(rb[2].x, rb[2].y); b1.y = pk2(rb[2].z, rb[2].w);
        b1.z = pk2(rb[3].x, rb[3].y); b1.w = pk2(rb[3].z, rb[3].w);
        *(uint4*)(Bs + srow * LDA + sseg * 16)     = b0;
        *(uint4*)(Bs + srow * LDA + sseg * 16 + 8) = b1;
    };

    const int NKT = H_DIM / BK;   // 16
    loadAB(0);
    for (int kt = 0; kt < NKT; kt++) {
        stage();
        __syncthreads();
        if (kt + 1 < NKT) loadAB(kt + 1);   // prefetch in flight across MFMA below
#pragma unroll
        for (int ks = 0; ks < BK / 32; ks++) {
            const int kloc = ks * 32 + (lane >> 4) * 8;
            bf16x8 af[2], bfr[4];
#pragma unroll
            for (int i = 0; i < 2; i++)
                af[i] = *(const bf16x8*)(As + (wm + i * 16 + (lane & 15)) * LDA + kloc);
#pragma unroll
            for (int j = 0; j < 4; j++)
                bfr[j] = *(const bf16x8*)(Bs + (wn + j * 16 + (lane & 15)) * LDA + kloc);
#pragma unroll
            for (int i = 0; i < 2; i++)
#pragma unroll
                for (int j = 0; j < 4; j++)
                    acc[i][j] = __builtin_amdgcn_mfma_f32_16x16x32_bf16(af[i], bfr[j], acc[i][j], 0, 0, 0);
        }
        __syncthreads();
    }

    // epilogue: silu + bf16 store (C/D layout: col=lane&15, row=(lane>>4)*4+reg)
#pragma unroll
    for (int i = 0; i < 2; i++) {
        const int mrow = wm + i * 16 + ((lane >> 4) << 2);
#pragma unroll
        for (int r = 0; r < 4; r++) {
            const int m = mTile * 128 + mrow + r;
            if (m < cnt) {
#pragma unroll
                for (int j = 0; j < 4; j++) {
                    float v = acc[i][j][r];
                    float s = v / (1.f + __expf(-v));
                    int col = fTile * 128 + wn + j * 16 + (lane & 15);
                    act[(size_t)(off + m) * F_DIM + col] = f2bf(s);
                }
            }
        }
    }
}

// ---------------- Down GEMM: out_slot = w * (act @ w2[e]^T), fp32 out ------------
__global__ __launch_bounds__(512) void down_gemm_kernel(
    const unsigned short* __restrict__ act, const float* __restrict__ w2,
    const int* __restrict__ counts,
    const float* __restrict__ row_weight,
    float* __restrict__ out_slot)
{
    const int e = blockIdx.z;
    const int cnt = counts[e];
    const int mTile = blockIdx.y;
    if (mTile * 128 >= cnt) return;
    const int hTile = blockIdx.x;
    const int off = expert_off(counts, e);

    __shared__ __align__(16) unsigned short As[128 * LDA];
    __shared__ __align__(16) unsigned short Bs[128 * LDA];

    const int tid = threadIdx.x;
    const int lane = tid & 63;
    const int wave = tid >> 6;
    const int wm = (wave >> 1) * 32;
    const int wn = (wave & 1) * 64;
    const int srow = tid >> 2;
    const int sseg = tid & 3;

    const int rowA = off + min(mTile * 128 + srow, cnt - 1);

    f32x4 acc[2][4];
#pragma unroll
    for (int i = 0; i < 2; i++)
#pragma unroll
        for (int j = 0; j < 4; j++) acc[i][j] = (f32x4)(0.f);

    const unsigned short* abase = act + (size_t)rowA * F_DIM + sseg * 16;
    const float* wbase = w2 + (size_t)e * H_DIM * F_DIM + (size_t)(hTile * 128 + srow) * F_DIM + sseg * 16;

    uint4 ra[2];
    float4 rb[4];
    auto loadAB = [&](int kt) {
        const int k0 = kt * BK;
        ra[0] = *(const uint4*)(abase + k0);
        ra[1] = *(const uint4*)(abase + k0 + 8);
#pragma unroll
        for (int j = 0; j < 4; j++)
            rb[j] = *(const float4*)(wbase + k0 + j * 4);
    };
    auto stage = [&] {
        *(uint4*)(As + srow * LDA + sseg * 16)     = ra[0];
        *(uint4*)(As + srow * LDA + sseg * 16 + 8) = ra[1];
        uint4 b0;
        b0.x = pk2(rb[0].x, rb[0].y); b0.y = pk2(rb[0].z, rb[0].w);
        b0.z = pk2(rb[1].x, rb[1].y); b0.w = pk2(rb[1].z, rb[1].w);
        uint4 b1;
        b1.x = pk2(rb[2].x, rb[2].y); b1.y = pk2(rb[2].z, rb[2].w);
        b1.z = pk2(rb[3].x, rb[3].y); b1.w = pk2(rb[3].z, rb[3].w);
        *(uint4*)(Bs + srow * LDA + sseg * 16)     = b0;
        *(uint4*)(Bs + srow * LDA + sseg * 16 + 8) = b1;
    };

    const int NKT = F_DIM / BK;   // 44
    loadAB(0);
    for (int kt = 0; kt < NKT; kt++) {
        stage();
        __syncthreads();
        if (kt + 1 < NKT) loadAB(kt + 1);
#pragma unroll
        for (int ks = 0; ks < BK / 32; ks++) {
            const int kloc = ks * 32 + (lane >> 4) * 8;
            bf16x8 af[2], bfr[4];
#pragma unroll
            for (int i = 0; i < 2; i++)
                af[i] = *(const bf16x8*)(As + (wm + i * 16 + (lane & 15)) * LDA + kloc);
#pragma unroll
            for (int j = 0; j < 4; j++)
                bfr[j] = *(const bf16x8*)(Bs + (wn + j * 16 + (lane & 15)) * LDA + kloc);
#pragma unroll
            for (int i = 0; i < 2; i++)
#pragma unroll
                for (int j = 0; j < 4; j++)
                    acc[i][j] = __builtin_amdgcn_mfma_f32_16x16x32_bf16(af[i], bfr[j], acc[i][j], 0, 0, 0);
        }
        __syncthreads();
    }

#pragma unroll
    for (int i = 0; i < 2; i++) {
        const int mrow = wm + i * 16 + ((lane >> 4) << 2);
#pragma unroll
        for (int r = 0; r < 4; r++) {
            const int m = mTile * 128 + mrow + r;
            if (m < cnt) {
                const float w = row_weight[e * N_TOK + m];
#pragma unroll
                for (int j = 0; j < 4; j++) {
                    int col = hTile * 128 + wn + j * 16 + (lane & 15);
                    out_slot[(size_t)(off + m) * H_DIM + col] = w * acc[i][j][r];
                }
            }
        }
    }
}

// ---------------- Combine: y[n] = slot0 + slot1 (weights already folded) ---------
__global__ __launch_bounds__(256) void combine_kernel(
    const float* __restrict__ out_slot, const int* __restrict__ counts,
    const int* __restrict__ slot_e, const int* __restrict__ slot_pos,
    float* __restrict__ out)
{
    const int n = blockIdx.x;
    const size_t r0 = expert_off(counts, slot_e[n * 2 + 0]) + slot_pos[n * 2 + 0];
    const size_t r1 = expert_off(counts, slot_e[n * 2 + 1]) + slot_pos[n * 2 + 1];
    const int t = threadIdx.x;
    const float4 a = *(const float4*)(out_slot + r0 * H_DIM + t * 4);
    const float4 b = *(const float4*)(out_slot + r1 * H_DIM + t * 4);
    float4 c; c.x = a.x + b.x; c.y = a.y + b.y; c.z = a.z + b.z; c.w = a.w + b.w;
    *(float4*)(out + (size_t)n * H_DIM + t * 4) = c;
}

extern "C" void kernel_launch(void* const* d_in, const int* in_sizes, int n_in,
                              void* d_out, int out_size, void* d_ws, size_t ws_size,
                              hipStream_t stream) {
    const float* x      = (const float*)d_in[0];
    const float* gate_w = (const float*)d_in[1];
    const float* w1     = (const float*)d_in[2];
    const float* w2     = (const float*)d_in[3];
    float* out = (float*)d_out;

    char* ws = (char*)d_ws;
    size_t o = 0;
    auto alloc = [&](size_t bytes) -> void* {
        void* p = ws + o;
        o = (o + bytes + 255) & ~(size_t)255;
        return p;
    };
    int*   counts     = (int*)  alloc(N_EXP * sizeof(int));
    int*   row_token  = (int*)  alloc((size_t)N_EXP * N_TOK * sizeof(int));
    float* row_weight = (float*)alloc((size_t)N_EXP * N_TOK * sizeof(float));
    int*   slot_e     = (int*)  alloc((size_t)N_TOK * 2 * sizeof(int));
    int*   slot_pos   = (int*)  alloc((size_t)N_TOK * 2 * sizeof(int));
    unsigned short* xb  = (unsigned short*)alloc((size_t)N_TOK * H_DIM * sizeof(unsigned short));
    unsigned short* act = (unsigned short*)alloc((size_t)N_TOK * 2 * F_DIM * sizeof(unsigned short));
    float* out_slot   = (float*)alloc((size_t)N_TOK * 2 * H_DIM * sizeof(float));

    hipMemsetAsync(counts, 0, N_EXP * sizeof(int), stream);

    router_kernel<<<N_TOK / 4, 256, 0, stream>>>(x, gate_w, counts, row_token, row_weight, slot_e, slot_pos, xb);
    up_gemm_kernel<<<dim3(F_DIM / 128, N_TOK / 128, N_EXP), 512, 0, stream>>>(
        xb, w1, counts, row_token, act);
    down_gemm_kernel<<<dim3(H_DIM / 128, N_TOK / 128, N_EXP), 512, 0, stream>>>(
        act, w2, counts, row_weight, out_slot);
    combine_kernel<<<N_TOK, 256, 0, stream>>>(out_slot, counts, slot_e, slot_pos, out);
}